// Round 1
// baseline (86.125 us; speedup 1.0000x reference)
//
#include <hip/hip_runtime.h>
#include <hip/hip_bf16.h>

typedef __attribute__((ext_vector_type(8))) short bf16x8;
typedef __attribute__((ext_vector_type(4))) float f32x4;

__device__ __forceinline__ short f2bf(float x) {
    __hip_bfloat16 t = __float2bfloat16(x);
    return __builtin_bit_cast(short, t);
}

// Problem constants (from reference setup): B=16, N=4096, K=16, hidden=64, dim=64
// rows = B*N*K = 1,048,576 ; groups of 16 rows = 65,536
// grid: 1024 blocks x 256 threads = 4096 waves, 16 groups per wave.

__global__ __launch_bounds__(256, 2) void ppe_kernel(
    const float* __restrict__ xyz,   // [16,4096,3]
    const float* __restrict__ dist,  // [16,4096,16]
    const float* __restrict__ W1,    // [10,64]
    const float* __restrict__ b1,    // [64]
    const float* __restrict__ W2,    // [64,64]
    const float* __restrict__ b2,    // [64]
    const int*   __restrict__ idx,   // [16,4096,16] (int32)
    float* __restrict__ out)         // [16,4096,16,64]
{
    const int lane = threadIdx.x & 63;
    const int wid  = (blockIdx.x * blockDim.x + threadIdx.x) >> 6; // 0..4095
    const int u    = lane >> 4;   // 0..3
    const int p    = lane & 15;   // A-row / D-col index

    // ---- hoist weights into registers (one-time per wave) ----
    // effective channels: wa[c] = W1[c]+W1[6+c] (center), wb[c] = W1[3+c]-W1[6+c]
    // (neighbor), wd = W1[9] (dist). Lane's 16 hidden dims: t*32 + u*8 + j.
    float wa[3][16], wb[3][16], wd[16], bb1[16];
#pragma unroll
    for (int t = 0; t < 2; ++t) {
        const int hd0 = t * 32 + u * 8;
#pragma unroll
        for (int j = 0; j < 8; ++j) {
            const int hd = hd0 + j;
            const int li = t * 8 + j;
#pragma unroll
            for (int c = 0; c < 3; ++c) {
                float wc_ = W1[c * 64 + hd];
                float wn_ = W1[(3 + c) * 64 + hd];
                float wr_ = W1[(6 + c) * 64 + hd];
                wa[c][li] = wc_ + wr_;
                wb[c][li] = wn_ - wr_;
            }
            wd[li]  = W1[9 * 64 + hd];
            bb1[li] = b1[hd];
        }
    }

    // W2 B-fragments: w2f[kt][ct][j] = W2[(kt*32 + u*8 + j)][ct*16 + p]
    bf16x8 w2f[2][4];
#pragma unroll
    for (int kt = 0; kt < 2; ++kt)
#pragma unroll
        for (int ct = 0; ct < 4; ++ct)
#pragma unroll
            for (int j = 0; j < 8; ++j)
                w2f[kt][ct][j] = f2bf(W2[(kt * 32 + u * 8 + j) * 64 + ct * 16 + p]);

    float b2r[4];
#pragma unroll
    for (int ct = 0; ct < 4; ++ct) b2r[ct] = b2[ct * 16 + p];

    // ---- main loop: one 16-row group per iteration ----
    for (int g = wid; g < 65536; g += 4096) {
        const int row = g * 16 + p;        // flattened (b,n,k)
        const int pn  = row >> 4;          // b*4096 + n  (K=16)
        const int bb  = row >> 16;         // batch       (N*K=65536)

        const int   nb = idx[row];
        const float d  = dist[row];
        const float* cptr = xyz + (size_t)pn * 3;
        const float c0 = cptr[0], c1 = cptr[1], c2 = cptr[2];
        const float* nptr = xyz + (size_t)(bb * 4096 + nb) * 3;
        const float n0 = nptr[0], n1 = nptr[1], n2 = nptr[2];

        // first layer: 16 hidden values this lane feeds into its A-fragments
        float h[16];
#pragma unroll
        for (int i = 0; i < 16; ++i) {
            float v = bb1[i];
            v = fmaf(c0, wa[0][i], v);
            v = fmaf(c1, wa[1][i], v);
            v = fmaf(c2, wa[2][i], v);
            v = fmaf(n0, wb[0][i], v);
            v = fmaf(n1, wb[1][i], v);
            v = fmaf(n2, wb[2][i], v);
            v = fmaf(d,  wd[i],    v);
            h[i] = fmaxf(v, 0.0f);
        }

        bf16x8 a0, a1;
#pragma unroll
        for (int j = 0; j < 8; ++j) { a0[j] = f2bf(h[j]); a1[j] = f2bf(h[8 + j]); }

        f32x4 acc[4];
#pragma unroll
        for (int ct = 0; ct < 4; ++ct) {
            acc[ct] = (f32x4){0.f, 0.f, 0.f, 0.f};
            acc[ct] = __builtin_amdgcn_mfma_f32_16x16x32_bf16(a0, w2f[0][ct], acc[ct], 0, 0, 0);
            acc[ct] = __builtin_amdgcn_mfma_f32_16x16x32_bf16(a1, w2f[1][ct], acc[ct], 0, 0, 0);
        }

        // store: D row = u*4 + r (point within group), D col = ct*16 + p
        float* obase = out + (size_t)g * 1024;  // 16 rows * 64 cols
#pragma unroll
        for (int ct = 0; ct < 4; ++ct)
#pragma unroll
            for (int r = 0; r < 4; ++r)
                obase[(u * 4 + r) * 64 + ct * 16 + p] = acc[ct][r] + b2r[ct];
    }
}

extern "C" void kernel_launch(void* const* d_in, const int* in_sizes, int n_in,
                              void* d_out, int out_size, void* d_ws, size_t ws_size,
                              hipStream_t stream) {
    const float* xyz  = (const float*)d_in[0];
    const float* dist = (const float*)d_in[1];
    const float* W1   = (const float*)d_in[2];
    const float* b1   = (const float*)d_in[3];
    const float* W2   = (const float*)d_in[4];
    const float* b2   = (const float*)d_in[5];
    const int*   idx  = (const int*)d_in[6];
    float* out = (float*)d_out;

    ppe_kernel<<<dim3(1024), dim3(256), 0, stream>>>(xyz, dist, W1, b1, W2, b2, idx, out);
}

// Round 2
// 84.059 us; speedup vs baseline: 1.0246x; 1.0246x over previous
//
#include <hip/hip_runtime.h>
#include <hip/hip_bf16.h>

typedef __attribute__((ext_vector_type(8))) short bf16x8;
typedef __attribute__((ext_vector_type(4))) float f32x4;

__device__ __forceinline__ short f2bf(float x) {
    __hip_bfloat16 t = __float2bfloat16(x);
    return __builtin_bit_cast(short, t);
}

// B=16, N=4096, K=16, hidden=64, dim=64
// rows = 1,048,576 ; 16-row groups = 65,536 (one group = one point's 16 neighbors)
// grid: 512 blocks x 256 threads = 2048 waves, 32 groups/wave (stride 2048).
// Software pipeline: loads for t+1/t+2 issued BEFORE stores of t, so the
// per-iteration s_waitcnt never drains the outstanding stores (in-order vmcnt).

__global__ __launch_bounds__(256, 2) void ppe_kernel(
    const float* __restrict__ xyz,   // [16,4096,3]
    const float* __restrict__ dist,  // [16,4096,16]
    const float* __restrict__ W1,    // [10,64]
    const float* __restrict__ b1,    // [64]
    const float* __restrict__ W2,    // [64,64]
    const float* __restrict__ b2,    // [64]
    const int*   __restrict__ idx,   // [16,4096,16] (int32)
    float* __restrict__ out)         // [16,4096,16,64]
{
    const int lane = threadIdx.x & 63;
    const int wid  = (blockIdx.x * blockDim.x + threadIdx.x) >> 6; // 0..2047
    const int u    = lane >> 4;   // 0..3
    const int p    = lane & 15;   // A-row / D-col index

    // ---- hoist weights into registers (one-time per wave) ----
    // wa[c] = W1[c]+W1[6+c] (center), wb[c] = W1[3+c]-W1[6+c] (neighbor), wd = W1[9].
    float wa[3][16], wb[3][16], wd[16], bb1[16];
#pragma unroll
    for (int t = 0; t < 2; ++t) {
        const int hd0 = t * 32 + u * 8;
#pragma unroll
        for (int j = 0; j < 8; ++j) {
            const int hd = hd0 + j;
            const int li = t * 8 + j;
#pragma unroll
            for (int c = 0; c < 3; ++c) {
                float wc_ = W1[c * 64 + hd];
                float wn_ = W1[(3 + c) * 64 + hd];
                float wr_ = W1[(6 + c) * 64 + hd];
                wa[c][li] = wc_ + wr_;
                wb[c][li] = wn_ - wr_;
            }
            wd[li]  = W1[9 * 64 + hd];
            bb1[li] = b1[hd];
        }
    }

    bf16x8 w2f[2][4];
#pragma unroll
    for (int kt = 0; kt < 2; ++kt)
#pragma unroll
        for (int ct = 0; ct < 4; ++ct)
#pragma unroll
            for (int j = 0; j < 8; ++j)
                w2f[kt][ct][j] = f2bf(W2[(kt * 32 + u * 8 + j) * 64 + ct * 16 + p]);

    float b2r[4];
#pragma unroll
    for (int ct = 0; ct < 4; ++ct) b2r[ct] = b2[ct * 16 + p];

    const int NIT = 32, STRIDE = 2048, NG = 65536;

    // ---- prologue ----
    const int g0 = wid;
    // stageA(0):
    const int row0 = g0 * 16 + p;
    int   nb0 = idx[row0];
    float dC  = dist[row0];
    // stageB(0):
    const float* cp0 = xyz + (size_t)g0 * 3;
    float cC0 = cp0[0], cC1 = cp0[1], cC2 = cp0[2];
    const float* np0 = xyz + ((size_t)((g0 >> 12) * 4096) + nb0) * 3;
    float nC0 = np0[0], nC1 = np0[1], nC2 = np0[2];
    // stageA(1):
    const int row1 = (g0 + STRIDE) * 16 + p;
    int   nbN = idx[row1];
    float dN  = dist[row1];

    for (int t = 0; t < NIT; ++t) {
        const int gc = g0 + t * STRIDE;

        // ---- 1. issue stageB(t+1): center + neighbor xyz (addr from nbN, resident) ----
        int gB = gc + STRIDE;       if (gB >= NG) gB = gc;   // clamped dummy on last iter
        const float* cpn = xyz + (size_t)gB * 3;
        float cL0 = cpn[0], cL1 = cpn[1], cL2 = cpn[2];
        const float* npn = xyz + ((size_t)((gB >> 12) * 4096) + nbN) * 3;
        float nL0 = npn[0], nL1 = npn[1], nL2 = npn[2];

        // ---- 2. issue stageA(t+2): idx + dist ----
        int gA = gc + 2 * STRIDE;   if (gA >= NG) gA = gc;
        const int rowA = gA * 16 + p;
        int   nbL = idx[rowA];
        float dL  = dist[rowA];

        // ---- 3. compute group t (all operands resident) ----
        float h[16];
#pragma unroll
        for (int i = 0; i < 16; ++i) {
            float v = bb1[i];
            v = fmaf(cC0, wa[0][i], v);
            v = fmaf(cC1, wa[1][i], v);
            v = fmaf(cC2, wa[2][i], v);
            v = fmaf(nC0, wb[0][i], v);
            v = fmaf(nC1, wb[1][i], v);
            v = fmaf(nC2, wb[2][i], v);
            v = fmaf(dC,  wd[i],    v);
            h[i] = fmaxf(v, 0.0f);
        }

        bf16x8 a0, a1;
#pragma unroll
        for (int j = 0; j < 8; ++j) { a0[j] = f2bf(h[j]); a1[j] = f2bf(h[8 + j]); }

        f32x4 acc[4];
#pragma unroll
        for (int ct = 0; ct < 4; ++ct) {
            acc[ct] = (f32x4){0.f, 0.f, 0.f, 0.f};
            acc[ct] = __builtin_amdgcn_mfma_f32_16x16x32_bf16(a0, w2f[0][ct], acc[ct], 0, 0, 0);
            acc[ct] = __builtin_amdgcn_mfma_f32_16x16x32_bf16(a1, w2f[1][ct], acc[ct], 0, 0, 0);
        }

        // ---- 4. stores (nontemporal: pure streaming output) ----
        float* obase = out + (size_t)gc * 1024;
#pragma unroll
        for (int ct = 0; ct < 4; ++ct)
#pragma unroll
            for (int r = 0; r < 4; ++r)
                __builtin_nontemporal_store(acc[ct][r] + b2r[ct],
                                            &obase[(u * 4 + r) * 64 + ct * 16 + p]);

        // ---- 5. rotate pipeline registers ----
        cC0 = cL0; cC1 = cL1; cC2 = cL2;
        nC0 = nL0; nC1 = nL1; nC2 = nL2;
        dC  = dN;  dN  = dL;  nbN = nbL;
    }
}

extern "C" void kernel_launch(void* const* d_in, const int* in_sizes, int n_in,
                              void* d_out, int out_size, void* d_ws, size_t ws_size,
                              hipStream_t stream) {
    const float* xyz  = (const float*)d_in[0];
    const float* dist = (const float*)d_in[1];
    const float* W1   = (const float*)d_in[2];
    const float* b1   = (const float*)d_in[3];
    const float* W2   = (const float*)d_in[4];
    const float* b2   = (const float*)d_in[5];
    const int*   idx  = (const int*)d_in[6];
    float* out = (float*)d_out;

    ppe_kernel<<<dim3(512), dim3(256), 0, stream>>>(xyz, dist, W1, b1, W2, b2, idx, out);
}

// Round 3
// 54.117 us; speedup vs baseline: 1.5915x; 1.5533x over previous
//
#include <hip/hip_runtime.h>
#include <hip/hip_bf16.h>

typedef __attribute__((ext_vector_type(8))) short bf16x8;
typedef __attribute__((ext_vector_type(4))) float f32x4;

__device__ __forceinline__ short f2bf(float x) {
    __hip_bfloat16 t = __float2bfloat16(x);
    return __builtin_bit_cast(short, t);
}

// B=16, N=4096, K=16, hidden=64, dim=64
// rows = 1,048,576 ; 16-row groups = 65,536 (group = one point's 16 neighbors)
// grid: 512 blocks x 256 threads = 2048 waves, 32 groups/wave (stride 2048).
//
// R3 change: MFMA D-fragment -> LDS (swizzled) -> linear 1KB-contiguous
// nontemporal dwordx4 stores. Direct fragment stores have 64B segments
// (half the txn granule) -> ~3.2 TB/s; linear dwordx4 matches the fill
// kernel's 6.8 TB/s pattern.

__global__ __launch_bounds__(256, 2) void ppe_kernel(
    const float* __restrict__ xyz,   // [16,4096,3]
    const float* __restrict__ dist,  // [16,4096,16]
    const float* __restrict__ W1,    // [10,64]
    const float* __restrict__ b1,    // [64]
    const float* __restrict__ W2,    // [64,64]
    const float* __restrict__ b2,    // [64]
    const int*   __restrict__ idx,   // [16,4096,16] (int32)
    float* __restrict__ out)         // [16,4096,16,64]
{
    __shared__ float sbuf[4][1024];  // 4 KB per wave, wave-private

    const int lane = threadIdx.x & 63;
    const int warp = threadIdx.x >> 6;
    const int wid  = (blockIdx.x * blockDim.x + threadIdx.x) >> 6; // 0..2047
    const int u    = lane >> 4;   // 0..3
    const int p    = lane & 15;   // 0..15

    float* const ws = &sbuf[warp][0];

    // ---- hoist weights into registers ----
    // wa[c] = W1[c]+W1[6+c] (center), wb[c] = W1[3+c]-W1[6+c] (neighbor), wd = W1[9].
    float wa[3][16], wb[3][16], wd[16], bb1[16];
#pragma unroll
    for (int t = 0; t < 2; ++t) {
        const int hd0 = t * 32 + u * 8;
#pragma unroll
        for (int j = 0; j < 8; ++j) {
            const int hd = hd0 + j;
            const int li = t * 8 + j;
#pragma unroll
            for (int c = 0; c < 3; ++c) {
                float wc_ = W1[c * 64 + hd];
                float wn_ = W1[(3 + c) * 64 + hd];
                float wr_ = W1[(6 + c) * 64 + hd];
                wa[c][li] = wc_ + wr_;
                wb[c][li] = wn_ - wr_;
            }
            wd[li]  = W1[9 * 64 + hd];
            bb1[li] = b1[hd];
        }
    }

    bf16x8 w2f[2][4];
#pragma unroll
    for (int kt = 0; kt < 2; ++kt)
#pragma unroll
        for (int ct = 0; ct < 4; ++ct)
#pragma unroll
            for (int j = 0; j < 8; ++j)
                w2f[kt][ct][j] = f2bf(W2[(kt * 32 + u * 8 + j) * 64 + ct * 16 + p]);

    float b2r[4];
#pragma unroll
    for (int ct = 0; ct < 4; ++ct) b2r[ct] = b2[ct * 16 + p];

    const int NIT = 32, STRIDE = 2048, NG = 65536;

    // ---- software-pipeline prologue ----
    const int g0 = wid;
    const int row0 = g0 * 16 + p;
    int   nb0 = idx[row0];
    float dC  = dist[row0];
    const float* cp0 = xyz + (size_t)g0 * 3;
    float cC0 = cp0[0], cC1 = cp0[1], cC2 = cp0[2];
    const float* np0 = xyz + ((size_t)((g0 >> 12) * 4096) + nb0) * 3;
    float nC0 = np0[0], nC1 = np0[1], nC2 = np0[2];
    const int row1 = (g0 + STRIDE) * 16 + p;
    int   nbN = idx[row1];
    float dN  = dist[row1];

    for (int t = 0; t < NIT; ++t) {
        const int gc = g0 + t * STRIDE;

        // ---- 1. issue neighbor/center xyz loads for t+1 (addr from resident nbN) ----
        int gB = gc + STRIDE;       if (gB >= NG) gB = gc;
        const float* cpn = xyz + (size_t)gB * 3;
        float cL0 = cpn[0], cL1 = cpn[1], cL2 = cpn[2];
        const float* npn = xyz + ((size_t)((gB >> 12) * 4096) + nbN) * 3;
        float nL0 = npn[0], nL1 = npn[1], nL2 = npn[2];

        // ---- 2. issue idx/dist loads for t+2 ----
        int gA = gc + 2 * STRIDE;   if (gA >= NG) gA = gc;
        const int rowA = gA * 16 + p;
        int   nbL = idx[rowA];
        float dL  = dist[rowA];

        // ---- 3. compute group t ----
        float h[16];
#pragma unroll
        for (int i = 0; i < 16; ++i) {
            float v = bb1[i];
            v = fmaf(cC0, wa[0][i], v);
            v = fmaf(cC1, wa[1][i], v);
            v = fmaf(cC2, wa[2][i], v);
            v = fmaf(nC0, wb[0][i], v);
            v = fmaf(nC1, wb[1][i], v);
            v = fmaf(nC2, wb[2][i], v);
            v = fmaf(dC,  wd[i],    v);
            h[i] = fmaxf(v, 0.0f);
        }

        bf16x8 a0, a1;
#pragma unroll
        for (int j = 0; j < 8; ++j) { a0[j] = f2bf(h[j]); a1[j] = f2bf(h[8 + j]); }

        f32x4 acc[4];
#pragma unroll
        for (int ct = 0; ct < 4; ++ct) {
            acc[ct] = (f32x4){0.f, 0.f, 0.f, 0.f};
            acc[ct] = __builtin_amdgcn_mfma_f32_16x16x32_bf16(a0, w2f[0][ct], acc[ct], 0, 0, 0);
            acc[ct] = __builtin_amdgcn_mfma_f32_16x16x32_bf16(a1, w2f[1][ct], acc[ct], 0, 0, 0);
        }

        // ---- 4. fragment -> LDS (swizzled; 2-way banks = free) ----
        // logical (row = point_local = u*4+r, col = dim = ct*16+p)
        // stored at dword addr row*64 + (col ^ (u<<2) ^ ((u&1)<<4))
#pragma unroll
        for (int ct = 0; ct < 4; ++ct) {
            const int cswz = (ct * 16 + p) ^ (u << 2) ^ ((u & 1) << 4);
            const int base = (u * 4) * 64 + cswz;
            ws[base      ] = acc[ct][0] + b2r[ct];
            ws[base +  64] = acc[ct][1] + b2r[ct];
            ws[base + 128] = acc[ct][2] + b2r[ct];
            ws[base + 192] = acc[ct][3] + b2r[ct];
        }

        // ---- 5. LDS -> linear global: 4 x 1KB fully-contiguous NT dwordx4 ----
        float* const obase = out + (size_t)gc * 1024;
#pragma unroll
        for (int i = 0; i < 4; ++i) {
            const int row  = i * 4 + u;                       // row>>2 == i
            const int cb   = (p * 4) ^ (i << 2) ^ ((i & 1) << 4);
            f32x4 v = *(const f32x4*)&ws[row * 64 + cb];
            __builtin_nontemporal_store(v, (f32x4*)&obase[i * 256 + lane * 4]);
        }

        // ---- 6. rotate pipeline registers ----
        cC0 = cL0; cC1 = cL1; cC2 = cL2;
        nC0 = nL0; nC1 = nL1; nC2 = nL2;
        dC  = dN;  dN  = dL;  nbN = nbL;
    }
}

extern "C" void kernel_launch(void* const* d_in, const int* in_sizes, int n_in,
                              void* d_out, int out_size, void* d_ws, size_t ws_size,
                              hipStream_t stream) {
    const float* xyz  = (const float*)d_in[0];
    const float* dist = (const float*)d_in[1];
    const float* W1   = (const float*)d_in[2];
    const float* b1   = (const float*)d_in[3];
    const float* W2   = (const float*)d_in[4];
    const float* b2   = (const float*)d_in[5];
    const int*   idx  = (const int*)d_in[6];
    float* out = (float*)d_out;

    ppe_kernel<<<dim3(512), dim3(256), 0, stream>>>(xyz, dist, W1, b1, W2, b2, idx, out);
}